// Round 11
// baseline (93.423 us; speedup 1.0000x reference)
//
#include <hip/hip_runtime.h>
#include <hip/hip_bf16.h>

// Problem constants
#define BATCH 128
#define NIN   1024
#define NFULL 4096
#define R1    48
#define R2    16
#define FCDIM 512
#define NOUT  10

// Workspace layout (float offsets). End = 11,538,432 floats (~44 MiB).
#define WS_C1  0
#define WS_D1  4096
#define WS_C2  8192
#define WS_D2  12288
#define WS_RC1 16384
#define WS_RD1 20480
#define WS_RC2 24576
#define WS_RD2 28672
#define WS_P1  32768                      // p1 hi/lo bf16 planes (131072 f32 slots)
#define WS_P2  (WS_P1 + BATCH*NIN)        // 163840  p2 hi/lo planes (524288 f32 slots)
#define WS_PT1 (WS_P2 + BATCH*NFULL)      // 688128  S1 = M1^T (4096 x 1024 fp32)
#define WS_P2M (WS_PT1 + NFULL*NIN)       // 4882432 (512 x 4096 fp32)
#define WS_CT1 (WS_P2M + FCDIM*NFULL)     // 6979584 (64 x 5120 chunk totals -> OFF1)
#define WS_CT2 (WS_CT1 + 64*5120)         // 7307264 (8 x 4608 chunk totals -> OFF2)
#define WS_VP1 (WS_CT2 + 8*4608)          // 7344128 (4 x 128 x 4096 L1 partials)
#define WS_VP2 (WS_VP1 + 4*BATCH*NFULL)   // 9441280 (32 x 128 x 512 L2 partials)
#define WS_END (WS_VP2 + 32*BATCH*FCDIM)  // 11538432

// Scan geometry: 64-row chunks along the row axis of each stored matrix.
#define NCH1 64                 // S1 has 4096 rows
#define NCH2 8                  // M2 has 512 rows
#define CTLD1 5120              // 5119 diagonals
#define CTLD2 4608              // 4607 diagonals

typedef __attribute__((ext_vector_type(8))) short bf16x8;   // 8 bf16 (raw bits)
typedef __attribute__((ext_vector_type(4))) float f32x4;

__device__ __forceinline__ unsigned short f2b(float f) {    // f32 -> bf16 bits, RNE
    unsigned u = __builtin_bit_cast(unsigned, f);
    return (unsigned short)((u + 0x7fffu + ((u >> 16) & 1u)) >> 16);
}
__device__ __forceinline__ float b2f(unsigned short h) {
    unsigned u = ((unsigned)h) << 16;
    return __builtin_bit_cast(float, u);
}
#define MFMA16(a, b, c) __builtin_amdgcn_mfma_f32_16x16x32_bf16(a, b, c, 0, 0, 0)

// ---------------------------------------------------------------------------
// prep: blocks 0-3 store cumprods c1,d1,c2,d2 (+ reciprocals); 4-35 p1 hi/lo.
__global__ void __launch_bounds__(256) prep_fused(
    const float* __restrict__ x, const float* __restrict__ sA1,
    const float* __restrict__ sB1, const float* __restrict__ sA2,
    const float* __restrict__ sB2, float* __restrict__ ws) {
    __shared__ float cd[4096];
    __shared__ float tot[256];
    int b = blockIdx.x, t = threadIdx.x;
    const float* src = (b == 0) ? sA1 : (b == 1) ? sB1 : (b == 2) ? sA2
                      : (b == 3) ? sB2 : sB1;      // p1 blocks need d1 (sB1)
    float loc[16];
    float prod = 1.f;
#pragma unroll
    for (int u = 0; u < 16; ++u) {
        int idx = t * 16 + u;
        float e = (idx == 0) ? 1.f : src[idx - 1];
        prod *= e;
        loc[u] = prod;
    }
    tot[t] = prod;
    __syncthreads();
    for (int off = 1; off < 256; off <<= 1) {
        float v = (t >= off) ? tot[t - off] : 1.f;
        __syncthreads();
        tot[t] *= v;
        __syncthreads();
    }
    float excl = (t == 0) ? 1.f : tot[t - 1];
#pragma unroll
    for (int u = 0; u < 16; ++u) cd[t * 16 + u] = excl * loc[u];
    __syncthreads();

    if (b < 4) {
        float* dst = ws + (size_t)b * 4096;            // c1,d1,c2,d2
        float* rdst = ws + WS_RC1 + (size_t)b * 4096;  // rc1,rd1,rc2,rd2
#pragma unroll
        for (int u = 0; u < 16; ++u) {
            int i = t + u * 256;
            dst[i] = cd[i];
            rdst[i] = 1.f / cd[i];
        }
    } else {
        unsigned short* p1h = (unsigned short*)(ws + WS_P1);
        unsigned short* p1l = p1h + BATCH * NIN;
        int row0 = (b - 4) * 4;
#pragma unroll
        for (int u = 0; u < 16; ++u) {
            int lin = t + u * 256;                 // 0..4095
            int row = row0 + (lin >> 10), col = lin & 1023;
            float f = x[(size_t)row * NIN + col] * cd[col];
            unsigned short h = f2b(f);
            p1h[(size_t)row * NIN + col] = h;
            p1l[(size_t)row * NIN + col] = f2b(f - b2f(h));
        }
    }
}

// ---------------------------------------------------------------------------
// Rank-K outer-product GEMMs, 1D grid (1536 blocks).
//  bid < 1024: S1[i][m] = sum_r (G1[r][i]*rc1[i]) * (H1[r][m]*rd1[m])
//              M=4096 (64 y-tiles), N=1024 (16 x-tiles), ldc=1024
//  bid >=1024: M2[i][m] = sum_r (G2[r][i]*rc2[i]) * (H2[r][m]*rd2[m])
//              M=512 (8 y-tiles), N=4096 (64 x-tiles), ldc=4096
__global__ void __launch_bounds__(256) gemm_rank_kernel(
    const float* __restrict__ G1, const float* __restrict__ H1,
    const float* __restrict__ G2, const float* __restrict__ H2,
    float* __restrict__ ws) {
    int bid = blockIdx.x;
    const float *A, *B, *mulA, *mulB;
    float* C;
    int Kr, ldc, m0, n0;
    if (bid < 1024) {
        A = G1; B = H1;
        mulA = ws + WS_RC1; mulB = ws + WS_RD1;
        C = ws + WS_PT1; Kr = R1; ldc = NIN;
        n0 = (bid & 15) * 64; m0 = (bid >> 4) * 64;
    } else {
        int b = bid - 1024;
        A = G2; B = H2;
        mulA = ws + WS_RC2; mulB = ws + WS_RD2;
        C = ws + WS_P2M; Kr = R2; ldc = NFULL;
        n0 = (b & 63) * 64; m0 = (b >> 6) * 64;
    }
    __shared__ float As[R1 * 68];
    __shared__ float Bs[R1 * 68];
    int tid = threadIdx.x;
    int tx = tid & 15, ty = tid >> 4;
    int nf4 = Kr * 16;
    for (int lin = tid; lin < nf4; lin += 256) {
        int r = lin >> 4, i4 = lin & 15;
        float4 va = *(const float4*)&A[(size_t)r * NFULL + m0 + i4 * 4];
        float4 da = *(const float4*)&mulA[m0 + i4 * 4];
        va.x *= da.x; va.y *= da.y; va.z *= da.z; va.w *= da.w;
        *(float4*)&As[r * 68 + i4 * 4] = va;
        float4 vb = *(const float4*)&B[(size_t)r * NFULL + n0 + i4 * 4];
        float4 db = *(const float4*)&mulB[n0 + i4 * 4];
        vb.x *= db.x; vb.y *= db.y; vb.z *= db.z; vb.w *= db.w;
        *(float4*)&Bs[r * 68 + i4 * 4] = vb;
    }
    __syncthreads();
    float acc[4][4] = {};
#pragma unroll 8
    for (int r = 0; r < Kr; ++r) {
        float4 a4 = *(const float4*)&As[r * 68 + ty * 4];
        float4 b4 = *(const float4*)&Bs[r * 68 + tx * 4];
        acc[0][0] += a4.x * b4.x; acc[0][1] += a4.x * b4.y;
        acc[0][2] += a4.x * b4.z; acc[0][3] += a4.x * b4.w;
        acc[1][0] += a4.y * b4.x; acc[1][1] += a4.y * b4.y;
        acc[1][2] += a4.y * b4.z; acc[1][3] += a4.y * b4.w;
        acc[2][0] += a4.z * b4.x; acc[2][1] += a4.z * b4.y;
        acc[2][2] += a4.z * b4.z; acc[2][3] += a4.z * b4.w;
        acc[3][0] += a4.w * b4.x; acc[3][1] += a4.w * b4.y;
        acc[3][2] += a4.w * b4.z; acc[3][3] += a4.w * b4.w;
    }
#pragma unroll
    for (int i = 0; i < 4; ++i) {
        int m = m0 + ty * 4 + i;
        *(float4*)&C[(size_t)m * ldc + n0 + tx * 4] =
            make_float4(acc[i][0], acc[i][1], acc[i][2], acc[i][3]);
    }
}

// ---------------------------------------------------------------------------
// Chunked diagonal prefix sum, phase 1. Recurrence P[i][m] += P[i-1][m-1].
// which=0: S1 (4096 x 1024, 64 chunks); which=1: M2 (512 x 4096, 8 chunks).
__global__ void diag_scan_p1(float* __restrict__ ws) {
    const int which = blockIdx.z;
    const int nch   = which == 0 ? NCH1 : NCH2;
    if (blockIdx.y >= (unsigned)nch) return;
    float* P        = ws + (which == 0 ? WS_PT1 : WS_P2M);
    float* ctot     = ws + (which == 0 ? WS_CT1 : WS_CT2);
    const int R     = which == 0 ? NFULL : FCDIM;
    const int C     = which == 0 ? NIN : NFULL;
    const int nd    = R + C - 1;
    const int ctld  = which == 0 ? CTLD1 : CTLD2;
    int t = blockIdx.x * 256 + threadIdx.x;
    if (t >= nd) return;
    int doff = t - (R - 1);                        // m - i
    int z = blockIdx.y;
    int i0 = z * 64;
    int ilo = max(i0, -doff);
    int ihi = min(i0 + 64, min(C - doff, R));
    float run = 0.f;
    if (ilo < ihi) {
        float* p = P + (size_t)ilo * C + (ilo + doff);
        const size_t step = (size_t)C + 1;
        int len = ihi - ilo;
        int s = 0;
        for (; s + 16 <= len; s += 16) {
            float v[16];
#pragma unroll
            for (int u = 0; u < 16; ++u) v[u] = p[u * step];
#pragma unroll
            for (int u = 0; u < 16; ++u) { run += v[u]; v[u] = run; }
#pragma unroll
            for (int u = 0; u < 16; ++u) p[u * step] = v[u];
            p += 16 * step;
        }
        for (; s < len; ++s) { float v = *p; run += v; *p = run; p += step; }
    }
    ctot[(size_t)z * ctld + t] = run;
}

// In-place exclusive prefix over z of the chunk totals: ctot -> OFF.
__global__ void off_prefix(float* __restrict__ ws) {
    const int which = blockIdx.z;
    float* ct      = ws + (which == 0 ? WS_CT1 : WS_CT2);
    const int ctld = which == 0 ? CTLD1 : CTLD2;
    const int nch  = which == 0 ? NCH1 : NCH2;
    int t = blockIdx.x * 256 + threadIdx.x;
    if (t >= ctld) return;
    float run = 0.f;
    for (int z = 0; z < nch; ++z) {
        float v = ct[(size_t)z * ctld + t];
        ct[(size_t)z * ctld + t] = run;
        run += v;
    }
}

// ---------------------------------------------------------------------------
// Layer-1 GEMM2 partials, LDS-free split-precision bf16 MFMA
// (D = Ah*Bh + Ah*Bl + Al*Bh). Grid (64,1,4) = 256 blocks, 512 thr = 8 waves;
// tile 128m x 64n; K-chunk 256 = 8 K32-steps; no barriers. B frags built per
// lane from k-contiguous S1 rows + OFF1 fold:
//   M1[k][n] = S1[n][k] + OFF1[n>>6][k - n + 4095]
__global__ void __launch_bounds__(512)
gemm2_l1_mfma(const unsigned short* __restrict__ p1h,
              const unsigned short* __restrict__ p1l,
              const float* __restrict__ S1, const float* __restrict__ OFF1,
              float* __restrict__ vp) {
    const int t = threadIdx.x;
    const int n0 = blockIdx.x * 64;
    const int kbase = blockIdx.z * 256;
    const int w = t >> 6, l = t & 63;
    const int mq = w >> 1, nh = w & 1;
    const int lm = l & 15, g = l >> 4;
    f32x4 zero = {0.f, 0.f, 0.f, 0.f};
    f32x4 acc00 = zero, acc01 = zero, acc10 = zero, acc11 = zero;
    const int nn0 = n0 + nh * 32 + lm;
    const int nn1 = nn0 + 16;
    const float* om0 = OFF1 + (size_t)(nn0 >> 6) * CTLD1 + (4095 - nn0);
    const float* om1 = OFF1 + (size_t)(nn1 >> 6) * CTLD1 + (4095 - nn1);
    const float* pm0 = S1 + (size_t)nn0 * NIN;
    const float* pm1 = S1 + (size_t)nn1 * NIN;

    float4 c0a, c0b, c1a, c1b, x0a, x0b, x1a, x1b;
    {
        int kk = kbase + 8 * g;
        c0a = *(const float4*)&pm0[kk]; c0b = *(const float4*)&pm0[kk + 4];
        c1a = *(const float4*)&pm1[kk]; c1b = *(const float4*)&pm1[kk + 4];
    }
#pragma unroll
    for (int ks = 0; ks < 8; ++ks) {
        int kk = kbase + ks * 32 + 8 * g;
        if (ks < 7) {
            int kn = kk + 32;
            x0a = *(const float4*)&pm0[kn]; x0b = *(const float4*)&pm0[kn + 4];
            x1a = *(const float4*)&pm1[kn]; x1b = *(const float4*)&pm1[kn + 4];
        }
        const unsigned short* pa = p1h + (size_t)(mq * 32 + lm) * NIN + kk;
        const unsigned short* pb = p1l + (size_t)(mq * 32 + lm) * NIN + kk;
        bf16x8 ah0 = *(const bf16x8*)pa, ah1 = *(const bf16x8*)(pa + 16 * NIN);
        bf16x8 al0 = *(const bf16x8*)pb, al1 = *(const bf16x8*)(pb + 16 * NIN);
        bf16x8 bh0, bl0, bh1, bl1;
        float m0v[8] = {c0a.x, c0a.y, c0a.z, c0a.w, c0b.x, c0b.y, c0b.z, c0b.w};
        float m1v[8] = {c1a.x, c1a.y, c1a.z, c1a.w, c1b.x, c1b.y, c1b.z, c1b.w};
#pragma unroll
        for (int r = 0; r < 8; ++r) {
            float f = m0v[r] + om0[kk + r];
            unsigned short h = f2b(f);
            bh0[r] = (short)h; bl0[r] = (short)f2b(f - b2f(h));
        }
#pragma unroll
        for (int r = 0; r < 8; ++r) {
            float f = m1v[r] + om1[kk + r];
            unsigned short h = f2b(f);
            bh1[r] = (short)h; bl1[r] = (short)f2b(f - b2f(h));
        }
        acc00 = MFMA16(ah0, bh0, acc00); acc10 = MFMA16(ah1, bh0, acc10);
        acc01 = MFMA16(ah0, bh1, acc01); acc11 = MFMA16(ah1, bh1, acc11);
        acc00 = MFMA16(ah0, bl0, acc00); acc10 = MFMA16(ah1, bl0, acc10);
        acc01 = MFMA16(ah0, bl1, acc01); acc11 = MFMA16(ah1, bl1, acc11);
        acc00 = MFMA16(al0, bh0, acc00); acc10 = MFMA16(al1, bh0, acc10);
        acc01 = MFMA16(al0, bh1, acc01); acc11 = MFMA16(al1, bh1, acc11);
        c0a = x0a; c0b = x0b; c1a = x1a; c1b = x1b;
    }
    float* dst = vp + (size_t)blockIdx.z * BATCH * NFULL;
    int row0 = mq * 32 + 4 * g;
    int col0 = n0 + nh * 32 + lm;
#pragma unroll
    for (int r = 0; r < 4; ++r) {
        dst[(size_t)(row0 + r) * NFULL + col0]           = acc00[r];
        dst[(size_t)(row0 + r) * NFULL + col0 + 16]      = acc01[r];
        dst[(size_t)(row0 + 16 + r) * NFULL + col0]      = acc10[r];
        dst[(size_t)(row0 + 16 + r) * NFULL + col0 + 16] = acc11[r];
    }
}

// reduce + epilogue: p2 = relu(c1*(sum of 4 partials) + b1) * d2 -> hi/lo planes
__global__ void reduce_l1_kernel(const float* __restrict__ vp, const float* __restrict__ c1,
                                 const float* __restrict__ b1, const float* __restrict__ d2,
                                 unsigned short* __restrict__ p2h,
                                 unsigned short* __restrict__ p2l) {
    int idx4 = blockIdx.x * 256 + threadIdx.x;     // 131072 float4s
    int base = idx4 * 4;
    int n = base & (NFULL - 1);
    float4 s = make_float4(0.f, 0.f, 0.f, 0.f);
#pragma unroll
    for (int z = 0; z < 4; ++z) {
        float4 v = *(const float4*)&vp[(size_t)z * BATCH * NFULL + base];
        s.x += v.x; s.y += v.y; s.z += v.z; s.w += v.w;
    }
    float4 cc = *(const float4*)&c1[n];
    float4 bb = *(const float4*)&b1[n];
    float4 dd = *(const float4*)&d2[n];
    float f[4];
    f[0] = fmaxf(cc.x * s.x + bb.x, 0.f) * dd.x;
    f[1] = fmaxf(cc.y * s.y + bb.y, 0.f) * dd.y;
    f[2] = fmaxf(cc.z * s.z + bb.z, 0.f) * dd.z;
    f[3] = fmaxf(cc.w * s.w + bb.w, 0.f) * dd.w;
    ushort4 hv, lv;
    unsigned short h;
    h = f2b(f[0]); hv.x = h; lv.x = f2b(f[0] - b2f(h));
    h = f2b(f[1]); hv.y = h; lv.y = f2b(f[1] - b2f(h));
    h = f2b(f[2]); hv.z = h; lv.z = f2b(f[2] - b2f(h));
    h = f2b(f[3]); hv.w = h; lv.w = f2b(f[3] - b2f(h));
    *(ushort4*)&p2h[base] = hv;
    *(ushort4*)&p2l[base] = lv;
}

// ---------------------------------------------------------------------------
// Layer-2 GEMM2, split-K=32 (chunk 128 = 4 K32-steps), LDS-free.
// Grid (8,1,32) = 256 blocks, 512 thr; tile 128m x 64n (R6-proven shape).
//   M2full[i][m] = M2[i][m] + OFF2[i>>6][m - i + 511]
__global__ void __launch_bounds__(512)
gemm2_l2_mfma(const unsigned short* __restrict__ p2h,
              const unsigned short* __restrict__ p2l,
              const float* __restrict__ M2, const float* __restrict__ OFF2,
              float* __restrict__ vp) {
    const int t = threadIdx.x;
    const int n0 = blockIdx.x * 64;
    const int kbase = blockIdx.z * 128;
    const int w = t >> 6, l = t & 63;
    const int mq = w >> 1, nh = w & 1;
    const int lm = l & 15, g = l >> 4;
    f32x4 zero = {0.f, 0.f, 0.f, 0.f};
    f32x4 acc00 = zero, acc01 = zero, acc10 = zero, acc11 = zero;
    const int nn0 = n0 + nh * 32 + lm;
    const int nn1 = nn0 + 16;
    const float* om0 = OFF2 + (size_t)(nn0 >> 6) * CTLD2 + (511 - nn0);
    const float* om1 = OFF2 + (size_t)(nn1 >> 6) * CTLD2 + (511 - nn1);
    const float* pm0 = M2 + (size_t)nn0 * NFULL;
    const float* pm1 = M2 + (size_t)nn1 * NFULL;

    float4 c0a, c0b, c1a, c1b, x0a, x0b, x1a, x1b;
    {
        int kk = kbase + 8 * g;
        c0a = *(const float4*)&pm0[kk]; c0b = *(const float4*)&pm0[kk + 4];
        c1a = *(const float4*)&pm1[kk]; c1b = *(const float4*)&pm1[kk + 4];
    }
#pragma unroll
    for (int ks = 0; ks < 4; ++ks) {
        int kk = kbase + ks * 32 + 8 * g;
        if (ks < 3) {
            int kn = kk + 32;
            x0a = *(const float4*)&pm0[kn]; x0b = *(const float4*)&pm0[kn + 4];
            x1a = *(const float4*)&pm1[kn]; x1b = *(const float4*)&pm1[kn + 4];
        }
        const unsigned short* pa = p2h + (size_t)(mq * 32 + lm) * NFULL + kk;
        const unsigned short* pb = p2l + (size_t)(mq * 32 + lm) * NFULL + kk;
        bf16x8 ah0 = *(const bf16x8*)pa, ah1 = *(const bf16x8*)(pa + 16 * NFULL);
        bf16x8 al0 = *(const bf16x8*)pb, al1 = *(const bf16x8*)(pb + 16 * NFULL);
        bf16x8 bh0, bl0, bh1, bl1;
        float m0v[8] = {c0a.x, c0a.y, c0a.z, c0a.w, c0b.x, c0b.y, c0b.z, c0b.w};
        float m1v[8] = {c1a.x, c1a.y, c1a.z, c1a.w, c1b.x, c1b.y, c1b.z, c1b.w};
#pragma unroll
        for (int r = 0; r < 8; ++r) {
            float f = m0v[r] + om0[kk + r];
            unsigned short h = f2b(f);
            bh0[r] = (short)h; bl0[r] = (short)f2b(f - b2f(h));
        }
#pragma unroll
        for (int r = 0; r < 8; ++r) {
            float f = m1v[r] + om1[kk + r];
            unsigned short h = f2b(f);
            bh1[r] = (short)h; bl1[r] = (short)f2b(f - b2f(h));
        }
        acc00 = MFMA16(ah0, bh0, acc00); acc10 = MFMA16(ah1, bh0, acc10);
        acc01 = MFMA16(ah0, bh1, acc01); acc11 = MFMA16(ah1, bh1, acc11);
        acc00 = MFMA16(ah0, bl0, acc00); acc10 = MFMA16(ah1, bl0, acc10);
        acc01 = MFMA16(ah0, bl1, acc01); acc11 = MFMA16(ah1, bl1, acc11);
        acc00 = MFMA16(al0, bh0, acc00); acc10 = MFMA16(al1, bh0, acc10);
        acc01 = MFMA16(al0, bh1, acc01); acc11 = MFMA16(al1, bh1, acc11);
        c0a = x0a; c0b = x0b; c1a = x1a; c1b = x1b;
    }
    float* dst = vp + (size_t)blockIdx.z * BATCH * FCDIM;
    int row0 = mq * 32 + 4 * g;
    int col0 = n0 + nh * 32 + lm;
#pragma unroll
    for (int r = 0; r < 4; ++r) {
        dst[(size_t)(row0 + r) * FCDIM + col0]           = acc00[r];
        dst[(size_t)(row0 + r) * FCDIM + col0 + 16]      = acc01[r];
        dst[(size_t)(row0 + 16 + r) * FCDIM + col0]      = acc10[r];
        dst[(size_t)(row0 + 16 + r) * FCDIM + col0 + 16] = acc11[r];
    }
}

// ---------------------------------------------------------------------------
// Fused L2 reduce + epilogue + logits. One block per batch row.
__global__ void fused_out_kernel(const float* __restrict__ vp, const float* __restrict__ c2,
                                 const float* __restrict__ b2, const float* __restrict__ Wl,
                                 const float* __restrict__ bl, float* __restrict__ out) {
    __shared__ float h2s[FCDIM];
    int b = blockIdx.x, t = threadIdx.x;
    for (int col = t; col < FCDIM; col += 256) {
        float s = 0.f;
#pragma unroll
        for (int z = 0; z < 32; ++z)
            s += vp[((size_t)z * BATCH + b) * FCDIM + col];
        h2s[col] = fmaxf(c2[col] * s + b2[col], 0.f);
    }
    __syncthreads();
    int w = t >> 6, lane = t & 63;
    for (int o = w; o < NOUT; o += 4) {
        float s = 0.f;
#pragma unroll
        for (int i = lane; i < FCDIM; i += 64) s += h2s[i] * Wl[(size_t)o * FCDIM + i];
#pragma unroll
        for (int off = 32; off > 0; off >>= 1) s += __shfl_down(s, off);
        if (lane == 0) out[(size_t)b * NOUT + o] = s + bl[o];
    }
}

// ---------------------------------------------------------------------------
extern "C" void kernel_launch(void* const* d_in, const int* in_sizes, int n_in,
                              void* d_out, int out_size, void* d_ws, size_t ws_size,
                              hipStream_t stream) {
    const float* x   = (const float*)d_in[0];
    const float* G1  = (const float*)d_in[1];
    const float* H1  = (const float*)d_in[2];
    const float* sA1 = (const float*)d_in[3];
    const float* sB1 = (const float*)d_in[4];
    const float* b1  = (const float*)d_in[5];
    const float* G2  = (const float*)d_in[6];
    const float* H2  = (const float*)d_in[7];
    const float* sA2 = (const float*)d_in[8];
    const float* sB2 = (const float*)d_in[9];
    const float* b2  = (const float*)d_in[10];
    const float* Wl  = (const float*)d_in[11];
    const float* bl  = (const float*)d_in[12];
    float* out = (float*)d_out;
    float* ws = (float*)d_ws;
    (void)in_sizes; (void)n_in; (void)out_size; (void)ws_size;

    unsigned short* p1h = (unsigned short*)(ws + WS_P1);
    unsigned short* p1l = p1h + BATCH * NIN;
    unsigned short* p2h = (unsigned short*)(ws + WS_P2);
    unsigned short* p2l = p2h + BATCH * NFULL;

    // 1. cumprods (+ reciprocals) + p1 hi/lo planes
    prep_fused<<<36, 256, 0, stream>>>(x, sA1, sB1, sA2, sB2, ws);

    // 2. Rank-K GEMMs: S1 = M1^T (4096x1024) and M2 (512x4096), 1D grid
    gemm_rank_kernel<<<1536, 256, 0, stream>>>(G1, H1, G2, H2, ws);

    // 3. Chunk-local diagonal scans (64-row chunks) + chunk totals
    diag_scan_p1<<<dim3(20, NCH1, 2), 256, 0, stream>>>(ws);
    //    chunk totals -> exclusive offsets (in place)
    off_prefix<<<dim3(20, 1, 2), 256, 0, stream>>>(ws);

    // 4. GEMM2 layer 1 (LDS-free, split-K=4, 256 blocks) -> 4 partials
    gemm2_l1_mfma<<<dim3(64, 1, 4), 512, 0, stream>>>(p1h, p1l, ws + WS_PT1,
                                                      ws + WS_CT1, ws + WS_VP1);
    //    reduce + epilogue -> p2 hi/lo planes
    reduce_l1_kernel<<<512, 256, 0, stream>>>(ws + WS_VP1, ws + WS_C1, b1, ws + WS_D2,
                                              p2h, p2l);

    // 5. GEMM2 layer 2 (LDS-free, split-K=32, 256 blocks) -> partials
    gemm2_l2_mfma<<<dim3(8, 1, 32), 512, 0, stream>>>(p2h, p2l, ws + WS_P2M,
                                                      ws + WS_CT2, ws + WS_VP2);

    // 6. fused reduce + epilogue + logits
    fused_out_kernel<<<BATCH, 256, 0, stream>>>(ws + WS_VP2, ws + WS_C2, b2, Wl, bl, out);
}

// Round 12
// 70.649 us; speedup vs baseline: 1.3224x; 1.3224x over previous
//
#include <hip/hip_runtime.h>
#include <hip/hip_bf16.h>

// Problem constants
#define BATCH 128
#define NIN   1024
#define NFULL 4096
#define R1    48
#define R2    16
#define FCDIM 512
#define NOUT  10

// Workspace layout (float offsets). End = 11,866,112 floats (~45.3 MiB).
#define WS_C1  0
#define WS_D1  4096
#define WS_C2  8192
#define WS_D2  12288
#define WS_Q1  16384
#define WS_GP1 (WS_Q1 + R1*NFULL)        // 212992
#define WS_Q2  (WS_GP1 + R1*NFULL)       // 409600
#define WS_GP2 (WS_Q2 + R2*NFULL)        // 475136
#define WS_P1  (WS_GP2 + R2*NFULL)       // 540672  (p1 hi/lo bf16 planes)
#define WS_P2  (WS_P1 + BATCH*NIN)       // 671744  (p2 hi/lo planes)
#define WS_H2  (WS_P2 + BATCH*NFULL)     // 1196032 (spare)
#define WS_PT1 (WS_H2 + BATCH*FCDIM)     // 1261568  (1024 x 4096 fp32)
#define WS_P2M (WS_PT1 + NIN*NFULL)      // 5455872  (512 x 4096 fp32)
#define WS_CT1 (WS_P2M + FCDIM*NFULL)    // 7553024  (16 x 5120 chunk totals -> OFF1)
#define WS_CT2 (WS_CT1 + 16*5120)        // 7634944  (8 x 4608 chunk totals -> OFF2)
#define WS_VP1 (WS_CT2 + 8*4608)         // 7671808  (4 x 128 x 4096 L1 partials)
#define WS_VP2 (WS_VP1 + 4*BATCH*NFULL)  // 9768960  (32 x 128 x 512 L2 partials)
#define WS_END (WS_VP2 + 32*BATCH*FCDIM) // 11866112

// Scan geometry: both matrices use 64-row chunks.
#define NCH1 16
#define NCH2 8
#define CHROWS 64
#define CTLD1 5120
#define CTLD2 4608

typedef __attribute__((ext_vector_type(8))) short bf16x8;   // 8 bf16 (raw bits)
typedef __attribute__((ext_vector_type(4))) float f32x4;

__device__ __forceinline__ unsigned short f2b(float f) {    // f32 -> bf16 bits, RNE
    unsigned u = __builtin_bit_cast(unsigned, f);
    return (unsigned short)((u + 0x7fffu + ((u >> 16) & 1u)) >> 16);
}
__device__ __forceinline__ float b2f(unsigned short h) {
    unsigned u = ((unsigned)h) << 16;
    return __builtin_bit_cast(float, u);
}
#define MFMA16(a, b, c) __builtin_amdgcn_mfma_f32_16x16x32_bf16(a, b, c, 0, 0, 0)

// ---------------------------------------------------------------------------
// Fused cumprod + elementwise prep. 160 blocks x 256 threads.
__global__ void __launch_bounds__(256) prep_fused(
    const float* __restrict__ x, const float* __restrict__ G1,
    const float* __restrict__ H1, const float* __restrict__ G2,
    const float* __restrict__ H2, const float* __restrict__ sA1,
    const float* __restrict__ sB1, const float* __restrict__ sA2,
    const float* __restrict__ sB2, float* __restrict__ ws) {
    __shared__ float cd[4096];
    __shared__ float tot[256];
    int b = blockIdx.x, t = threadIdx.x;
    const float* src;
    int kind, r;
    if (b < 48)       { kind = 0; r = b;       src = sB1; }   // q1 needs d1
    else if (b < 96)  { kind = 1; r = b - 48;  src = sA1; }   // gp1 needs c1
    else if (b < 112) { kind = 2; r = b - 96;  src = sB2; }   // q2 needs d2
    else if (b < 128) { kind = 3; r = b - 112; src = sA2; }   // gp2 needs c2
    else              { kind = 4; r = b - 128; src = sB1; }   // p1 needs d1
    float loc[16];
    float prod = 1.f;
#pragma unroll
    for (int u = 0; u < 16; ++u) {
        int idx = t * 16 + u;
        float e = (idx == 0) ? 1.f : src[idx - 1];
        prod *= e;
        loc[u] = prod;
    }
    tot[t] = prod;
    __syncthreads();
    for (int off = 1; off < 256; off <<= 1) {
        float v = (t >= off) ? tot[t - off] : 1.f;
        __syncthreads();
        tot[t] *= v;
        __syncthreads();
    }
    float excl = (t == 0) ? 1.f : tot[t - 1];
#pragma unroll
    for (int u = 0; u < 16; ++u) cd[t * 16 + u] = excl * loc[u];
    __syncthreads();

    if (kind == 0) {
        const float* s0 = H1 + (size_t)r * NFULL;
        float* dst = ws + WS_Q1 + (size_t)r * NFULL;
#pragma unroll
        for (int u = 0; u < 16; ++u) { int i = t + u * 256; dst[i] = s0[i] / cd[i]; }
        if (r == 0) { float* d1 = ws + WS_D1;
#pragma unroll
            for (int u = 0; u < 16; ++u) { int i = t + u * 256; d1[i] = cd[i]; } }
    } else if (kind == 1) {
        const float* s0 = G1 + (size_t)r * NFULL;
        float* dst = ws + WS_GP1 + (size_t)r * NFULL;
#pragma unroll
        for (int u = 0; u < 16; ++u) { int i = t + u * 256; dst[i] = s0[i] / cd[i]; }
        if (r == 0) { float* c1 = ws + WS_C1;
#pragma unroll
            for (int u = 0; u < 16; ++u) { int i = t + u * 256; c1[i] = cd[i]; } }
    } else if (kind == 2) {
        const float* s0 = H2 + (size_t)r * NFULL;
        float* dst = ws + WS_Q2 + (size_t)r * NFULL;
#pragma unroll
        for (int u = 0; u < 16; ++u) { int i = t + u * 256; dst[i] = s0[i] / cd[i]; }
        if (r == 0) { float* d2 = ws + WS_D2;
#pragma unroll
            for (int u = 0; u < 16; ++u) { int i = t + u * 256; d2[i] = cd[i]; } }
    } else if (kind == 3) {
        const float* s0 = G2 + (size_t)r * NFULL;
        float* dst = ws + WS_GP2 + (size_t)r * NFULL;
#pragma unroll
        for (int u = 0; u < 16; ++u) { int i = t + u * 256; dst[i] = s0[i] / cd[i]; }
        if (r == 0) { float* c2 = ws + WS_C2;
#pragma unroll
            for (int u = 0; u < 16; ++u) { int i = t + u * 256; c2[i] = cd[i]; } }
    } else {
        unsigned short* p1h = (unsigned short*)(ws + WS_P1);
        unsigned short* p1l = p1h + BATCH * NIN;
        int row0 = r * 4;
#pragma unroll
        for (int u = 0; u < 16; ++u) {
            int lin = t + u * 256;                 // 0..4095
            int row = row0 + (lin >> 10), col = lin & 1023;
            float f = x[(size_t)row * NIN + col] * cd[col];
            unsigned short h = f2b(f);
            p1h[(size_t)row * NIN + col] = h;
            p1l[(size_t)row * NIN + col] = f2b(f - b2f(h));
        }
    }
}

// ---------------------------------------------------------------------------
// Rank-K outer-product GEMMs, both in one launch (z: 0 = M1, 1 = M2).
__global__ void __launch_bounds__(256) gemm_rank_kernel(float* __restrict__ ws) {
    const int which = blockIdx.z;
    if (which == 1 && blockIdx.y >= 8) return;
    const float* A = ws + (which == 0 ? WS_Q1  : WS_GP2);
    const float* B = ws + (which == 0 ? WS_GP1 : WS_Q2);
    float* C       = ws + (which == 0 ? WS_PT1 : WS_P2M);
    const int Kr   = which == 0 ? R1 : R2;
    __shared__ float As[R1 * 68];
    __shared__ float Bs[R1 * 68];
    int tid = threadIdx.x;
    int tx = tid & 15, ty = tid >> 4;
    int n0 = blockIdx.x * 64;
    int m0 = blockIdx.y * 64;
    int nf4 = Kr * 16;
    for (int lin = tid; lin < nf4; lin += 256) {
        int r = lin >> 4, i4 = lin & 15;
        *(float4*)&As[r * 68 + i4 * 4] = *(const float4*)&A[(size_t)r * NFULL + m0 + i4 * 4];
        *(float4*)&Bs[r * 68 + i4 * 4] = *(const float4*)&B[(size_t)r * NFULL + n0 + i4 * 4];
    }
    __syncthreads();
    float acc[4][4] = {};
#pragma unroll 8
    for (int r = 0; r < Kr; ++r) {
        float4 a4 = *(const float4*)&As[r * 68 + ty * 4];
        float4 b4 = *(const float4*)&Bs[r * 68 + tx * 4];
        acc[0][0] += a4.x * b4.x; acc[0][1] += a4.x * b4.y;
        acc[0][2] += a4.x * b4.z; acc[0][3] += a4.x * b4.w;
        acc[1][0] += a4.y * b4.x; acc[1][1] += a4.y * b4.y;
        acc[1][2] += a4.y * b4.z; acc[1][3] += a4.y * b4.w;
        acc[2][0] += a4.z * b4.x; acc[2][1] += a4.z * b4.y;
        acc[2][2] += a4.z * b4.z; acc[2][3] += a4.z * b4.w;
        acc[3][0] += a4.w * b4.x; acc[3][1] += a4.w * b4.y;
        acc[3][2] += a4.w * b4.z; acc[3][3] += a4.w * b4.w;
    }
#pragma unroll
    for (int i = 0; i < 4; ++i) {
        int m = m0 + ty * 4 + i;
        *(float4*)&C[(size_t)m * NFULL + n0 + tx * 4] =
            make_float4(acc[i][0], acc[i][1], acc[i][2], acc[i][3]);
    }
}

// ---------------------------------------------------------------------------
// Chunked diagonal prefix sum, phase 1. 64-row chunks for both matrices.
__global__ void diag_scan_p1(float* __restrict__ ws) {
    const int which = blockIdx.z;
    const int nch   = which == 0 ? NCH1 : NCH2;
    if (blockIdx.y >= (unsigned)nch) return;
    float* P        = ws + (which == 0 ? WS_PT1 : WS_P2M);
    float* ctot     = ws + (which == 0 ? WS_CT1 : WS_CT2);
    const int R     = which == 0 ? NIN : FCDIM;
    const int nd    = R + NFULL - 1;
    const int ctld  = which == 0 ? CTLD1 : CTLD2;
    int t = blockIdx.x * 256 + threadIdx.x;
    if (t >= nd) return;
    int doff = t - (R - 1);
    int z = blockIdx.y;
    int m0 = z * CHROWS;
    int mlo = max(m0, -doff);
    int mhi = min(m0 + CHROWS, min(NFULL - doff, R));
    float run = 0.f;
    if (mlo < mhi) {
        float* p = P + (size_t)mlo * NFULL + (mlo + doff);
        const size_t step = NFULL + 1;
        int len = mhi - mlo;
        int s = 0;
        for (; s + 16 <= len; s += 16) {
            float v[16];
#pragma unroll
            for (int u = 0; u < 16; ++u) v[u] = p[u * step];
#pragma unroll
            for (int u = 0; u < 16; ++u) { run += v[u]; v[u] = run; }
#pragma unroll
            for (int u = 0; u < 16; ++u) p[u * step] = v[u];
            p += 16 * step;
        }
        for (; s < len; ++s) { float v = *p; run += v; *p = run; p += step; }
    }
    ctot[(size_t)z * ctld + t] = run;
}

// In-place exclusive prefix over z of the chunk totals: ctot -> OFF.
__global__ void off_prefix(float* __restrict__ ws) {
    const int which = blockIdx.z;
    float* ct      = ws + (which == 0 ? WS_CT1 : WS_CT2);
    const int ctld = which == 0 ? CTLD1 : CTLD2;
    const int nch  = which == 0 ? NCH1 : NCH2;
    int t = blockIdx.x * 256 + threadIdx.x;
    if (t >= ctld) return;
    float run = 0.f;
    for (int z = 0; z < nch; ++z) {
        float v = ct[(size_t)z * ctld + t];
        ct[(size_t)z * ctld + t] = run;
        run += v;
    }
}

// ---------------------------------------------------------------------------
// Layer-1 GEMM2 partials via split-precision bf16 MFMA (D=Ah*Bh+Ah*Bl+Al*Bh).
// Grid (64,1,4) = 256 blocks, 512 thr = 8 waves; tile 128m x 64n; K-chunk 256
// (8 K32-steps), one-deep register pipeline. B: fp32 P1 + OFF1 -> hi/lo bf16
// in LDS. C/D mapping (m89-verified): col = lane&15, row = (lane>>4)*4 + reg.
#define L1_LOADA(H0, H1, L0, L1v, KS) { \
    int kk_ = kbase + (KS) * 32 + 8 * g; \
    const unsigned short* pa_ = p1h + (size_t)(mq * 32 + lm) * NIN + kk_; \
    const unsigned short* pb_ = p1l + (size_t)(mq * 32 + lm) * NIN + kk_; \
    H0 = *(const bf16x8*)pa_;  H1 = *(const bf16x8*)(pa_ + 16 * NIN); \
    L0 = *(const bf16x8*)pb_;  L1v = *(const bf16x8*)(pb_ + 16 * NIN); }

#define L1_LOADS(KS) { \
    int kg_ = kbase + (KS) * 32 + 2 * k2; \
    const float* pr_ = P1 + (size_t)kg_ * NFULL + n0 + 2 * n2; \
    float2 va_ = *(const float2*)pr_; \
    float2 vb_ = *(const float2*)(pr_ + NFULL); \
    const float* orow_ = OFF1 + (size_t)(kg_ >> 6) * CTLD1 + (1023 + n0 + 2 * n2 - kg_); \
    float om_ = orow_[-1], oc_ = orow_[0], op_ = orow_[1]; \
    f00 = va_.x + oc_; f01 = va_.y + op_; f10 = vb_.x + om_; f11 = vb_.y + oc_; }

#define L1_WRITES() { \
    unsigned short h00_ = f2b(f00), h10_ = f2b(f10), h01_ = f2b(f01), h11_ = f2b(f11); \
    int a0_ = (2 * n2) * 20 + k2; \
    Bh[a0_]      = (unsigned)h00_ | ((unsigned)h10_ << 16); \
    Bh[a0_ + 20] = (unsigned)h01_ | ((unsigned)h11_ << 16); \
    Bl[a0_]      = (unsigned)f2b(f00 - b2f(h00_)) | ((unsigned)f2b(f10 - b2f(h10_)) << 16); \
    Bl[a0_ + 20] = (unsigned)f2b(f01 - b2f(h01_)) | ((unsigned)f2b(f11 - b2f(h11_)) << 16); }

#define L1_COMPUTE(H0, H1, L0, L1v) { \
    int nb_ = (nh * 32 + lm) * 20 + 4 * g; \
    uint4 uh0_ = *(const uint4*)&Bh[nb_];       uint4 ul0_ = *(const uint4*)&Bl[nb_]; \
    uint4 uh1_ = *(const uint4*)&Bh[nb_ + 320]; uint4 ul1_ = *(const uint4*)&Bl[nb_ + 320]; \
    bf16x8 bh0_ = __builtin_bit_cast(bf16x8, uh0_), bl0_ = __builtin_bit_cast(bf16x8, ul0_); \
    bf16x8 bh1_ = __builtin_bit_cast(bf16x8, uh1_), bl1_ = __builtin_bit_cast(bf16x8, ul1_); \
    acc00 = MFMA16(H0, bh0_, acc00); acc10 = MFMA16(H1, bh0_, acc10); \
    acc01 = MFMA16(H0, bh1_, acc01); acc11 = MFMA16(H1, bh1_, acc11); \
    acc00 = MFMA16(H0, bl0_, acc00); acc10 = MFMA16(H1, bl0_, acc10); \
    acc01 = MFMA16(H0, bl1_, acc01); acc11 = MFMA16(H1, bl1_, acc11); \
    acc00 = MFMA16(L0, bh0_, acc00); acc10 = MFMA16(L1v, bh0_, acc10); \
    acc01 = MFMA16(L0, bh1_, acc01); acc11 = MFMA16(L1v, bh1_, acc11); }

#define L1_STEP(CH0, CH1, CL0, CL1, NH0, NH1, NL0, NL1, KS, LAST) \
    __syncthreads(); \
    L1_WRITES(); \
    if (!(LAST)) { L1_LOADS((KS) + 1); L1_LOADA(NH0, NH1, NL0, NL1, (KS) + 1); } \
    __syncthreads(); \
    L1_COMPUTE(CH0, CH1, CL0, CL1);

__global__ void __launch_bounds__(512)
gemm2_l1_mfma(const float* __restrict__ P1, const float* __restrict__ OFF1,
              const unsigned short* __restrict__ p1h,
              const unsigned short* __restrict__ p1l, float* __restrict__ vp) {
    __shared__ unsigned Bh[64 * 20];
    __shared__ unsigned Bl[64 * 20];
    const int t = threadIdx.x;
    const int n0 = blockIdx.x * 64;
    const int kbase = blockIdx.z * 256;
    const int w = t >> 6, l = t & 63;
    const int mq = w >> 1, nh = w & 1;
    const int lm = l & 15, g = l >> 4;
    const int k2 = t >> 5, n2 = t & 31;

    f32x4 zero = {0.f, 0.f, 0.f, 0.f};
    f32x4 acc00 = zero, acc01 = zero, acc10 = zero, acc11 = zero;
    bf16x8 ahA0, ahA1, alA0, alA1, ahB0, ahB1, alB0, alB1;
    float f00, f01, f10, f11;

    L1_LOADS(0);
    L1_LOADA(ahA0, ahA1, alA0, alA1, 0);
    L1_STEP(ahA0, ahA1, alA0, alA1, ahB0, ahB1, alB0, alB1, 0, 0)
    L1_STEP(ahB0, ahB1, alB0, alB1, ahA0, ahA1, alA0, alA1, 1, 0)
    L1_STEP(ahA0, ahA1, alA0, alA1, ahB0, ahB1, alB0, alB1, 2, 0)
    L1_STEP(ahB0, ahB1, alB0, alB1, ahA0, ahA1, alA0, alA1, 3, 0)
    L1_STEP(ahA0, ahA1, alA0, alA1, ahB0, ahB1, alB0, alB1, 4, 0)
    L1_STEP(ahB0, ahB1, alB0, alB1, ahA0, ahA1, alA0, alA1, 5, 0)
    L1_STEP(ahA0, ahA1, alA0, alA1, ahB0, ahB1, alB0, alB1, 6, 0)
    L1_STEP(ahB0, ahB1, alB0, alB1, ahA0, ahA1, alA0, alA1, 7, 1)

    float* dst = vp + (size_t)blockIdx.z * BATCH * NFULL;
    int row0 = mq * 32 + 4 * g;
    int col0 = n0 + nh * 32 + lm;
#pragma unroll
    for (int r = 0; r < 4; ++r) {
        dst[(size_t)(row0 + r) * NFULL + col0]           = acc00[r];
        dst[(size_t)(row0 + r) * NFULL + col0 + 16]      = acc01[r];
        dst[(size_t)(row0 + 16 + r) * NFULL + col0]      = acc10[r];
        dst[(size_t)(row0 + 16 + r) * NFULL + col0 + 16] = acc11[r];
    }
}

// reduce + epilogue: p2 = relu(c1*(sum of 4 partials) + b1) * d2 -> hi/lo planes
__global__ void reduce_l1_kernel(const float* __restrict__ vp, const float* __restrict__ c1,
                                 const float* __restrict__ b1, const float* __restrict__ d2,
                                 unsigned short* __restrict__ p2h,
                                 unsigned short* __restrict__ p2l) {
    int idx4 = blockIdx.x * 256 + threadIdx.x;     // 131072 float4s
    int base = idx4 * 4;
    int n = base & (NFULL - 1);
    float4 s = make_float4(0.f, 0.f, 0.f, 0.f);
#pragma unroll
    for (int z = 0; z < 4; ++z) {
        float4 v = *(const float4*)&vp[(size_t)z * BATCH * NFULL + base];
        s.x += v.x; s.y += v.y; s.z += v.z; s.w += v.w;
    }
    float4 cc = *(const float4*)&c1[n];
    float4 bb = *(const float4*)&b1[n];
    float4 dd = *(const float4*)&d2[n];
    float f[4];
    f[0] = fmaxf(cc.x * s.x + bb.x, 0.f) * dd.x;
    f[1] = fmaxf(cc.y * s.y + bb.y, 0.f) * dd.y;
    f[2] = fmaxf(cc.z * s.z + bb.z, 0.f) * dd.z;
    f[3] = fmaxf(cc.w * s.w + bb.w, 0.f) * dd.w;
    ushort4 hv, lv;
    unsigned short h;
    h = f2b(f[0]); hv.x = h; lv.x = f2b(f[0] - b2f(h));
    h = f2b(f[1]); hv.y = h; lv.y = f2b(f[1] - b2f(h));
    h = f2b(f[2]); hv.z = h; lv.z = f2b(f[2] - b2f(h));
    h = f2b(f[3]); hv.w = h; lv.w = f2b(f[3] - b2f(h));
    *(ushort4*)&p2h[base] = hv;
    *(ushort4*)&p2l[base] = lv;
}

// ---------------------------------------------------------------------------
// Layer-2 GEMM2 via split-precision bf16 MFMA. No LDS: B frags built per lane
// from k-contiguous M2 rows (M2 stored [n][k]) + OFF2 fold. Grid (8,1,32),
// 512 thr = 8 waves; tile 128m x 64n; K-chunk 128 (4 K32-steps).
__global__ void __launch_bounds__(512)
gemm2_l2_mfma(const unsigned short* __restrict__ p2h,
              const unsigned short* __restrict__ p2l,
              const float* __restrict__ M2, const float* __restrict__ OFF2,
              float* __restrict__ vp) {
    const int t = threadIdx.x;
    const int n0 = blockIdx.x * 64;
    const int kbase = blockIdx.z * 128;
    const int w = t >> 6, l = t & 63;
    const int mq = w >> 1, nh = w & 1;
    const int lm = l & 15, g = l >> 4;
    f32x4 zero = {0.f, 0.f, 0.f, 0.f};
    f32x4 acc00 = zero, acc01 = zero, acc10 = zero, acc11 = zero;
    const int nn0 = n0 + nh * 32 + lm;           // ni=0 B-row; ni=1 is nn0+16
    const int nn1 = nn0 + 16;
    const float* om0 = OFF2 + (size_t)(nn0 >> 6) * CTLD2 + (511 - nn0);
    const float* om1 = OFF2 + (size_t)(nn1 >> 6) * CTLD2 + (511 - nn1);
#pragma unroll
    for (int ks = 0; ks < 4; ++ks) {
        int kk = kbase + ks * 32 + 8 * g;
        const unsigned short* pa = p2h + (size_t)(mq * 32 + lm) * NFULL + kk;
        const unsigned short* pb = p2l + (size_t)(mq * 32 + lm) * NFULL + kk;
        bf16x8 ah0 = *(const bf16x8*)pa, ah1 = *(const bf16x8*)(pa + 16 * NFULL);
        bf16x8 al0 = *(const bf16x8*)pb, al1 = *(const bf16x8*)(pb + 16 * NFULL);
        bf16x8 bh0, bl0, bh1, bl1;
        {
            const float* pm = M2 + (size_t)nn0 * NFULL + kk;
#pragma unroll
            for (int r = 0; r < 8; ++r) {
                float f = pm[r] + om0[kk + r];
                unsigned short h = f2b(f);
                bh0[r] = (short)h; bl0[r] = (short)f2b(f - b2f(h));
            }
        }
        {
            const float* pm = M2 + (size_t)nn1 * NFULL + kk;
#pragma unroll
            for (int r = 0; r < 8; ++r) {
                float f = pm[r] + om1[kk + r];
                unsigned short h = f2b(f);
                bh1[r] = (short)h; bl1[r] = (short)f2b(f - b2f(h));
            }
        }
        acc00 = MFMA16(ah0, bh0, acc00); acc10 = MFMA16(ah1, bh0, acc10);
        acc01 = MFMA16(ah0, bh1, acc01); acc11 = MFMA16(ah1, bh1, acc11);
        acc00 = MFMA16(ah0, bl0, acc00); acc10 = MFMA16(ah1, bl0, acc10);
        acc01 = MFMA16(ah0, bl1, acc01); acc11 = MFMA16(ah1, bl1, acc11);
        acc00 = MFMA16(al0, bh0, acc00); acc10 = MFMA16(al1, bh0, acc10);
        acc01 = MFMA16(al0, bh1, acc01); acc11 = MFMA16(al1, bh1, acc11);
    }
    float* dst = vp + (size_t)blockIdx.z * BATCH * FCDIM;
    int row0 = mq * 32 + 4 * g;
    int col0 = n0 + nh * 32 + lm;
#pragma unroll
    for (int r = 0; r < 4; ++r) {
        dst[(size_t)(row0 + r) * FCDIM + col0]           = acc00[r];
        dst[(size_t)(row0 + r) * FCDIM + col0 + 16]      = acc01[r];
        dst[(size_t)(row0 + 16 + r) * FCDIM + col0]      = acc10[r];
        dst[(size_t)(row0 + 16 + r) * FCDIM + col0 + 16] = acc11[r];
    }
}

// ---------------------------------------------------------------------------
// Fused L2 reduce + epilogue + logits. One block per batch row.
__global__ void fused_out_kernel(const float* __restrict__ vp, const float* __restrict__ c2,
                                 const float* __restrict__ b2, const float* __restrict__ Wl,
                                 const float* __restrict__ bl, float* __restrict__ out) {
    __shared__ float h2s[FCDIM];
    int b = blockIdx.x, t = threadIdx.x;
    for (int col = t; col < FCDIM; col += 256) {
        float s = 0.f;
#pragma unroll
        for (int z = 0; z < 32; ++z)
            s += vp[((size_t)z * BATCH + b) * FCDIM + col];
        h2s[col] = fmaxf(c2[col] * s + b2[col], 0.f);
    }
    __syncthreads();
    int w = t >> 6, lane = t & 63;
    for (int o = w; o < NOUT; o += 4) {
        float s = 0.f;
#pragma unroll
        for (int i = lane; i < FCDIM; i += 64) s += h2s[i] * Wl[(size_t)o * FCDIM + i];
#pragma unroll
        for (int off = 32; off > 0; off >>= 1) s += __shfl_down(s, off);
        if (lane == 0) out[(size_t)b * NOUT + o] = s + bl[o];
    }
}

// ---------------------------------------------------------------------------
extern "C" void kernel_launch(void* const* d_in, const int* in_sizes, int n_in,
                              void* d_out, int out_size, void* d_ws, size_t ws_size,
                              hipStream_t stream) {
    const float* x   = (const float*)d_in[0];
    const float* G1  = (const float*)d_in[1];
    const float* H1  = (const float*)d_in[2];
    const float* sA1 = (const float*)d_in[3];
    const float* sB1 = (const float*)d_in[4];
    const float* b1  = (const float*)d_in[5];
    const float* G2  = (const float*)d_in[6];
    const float* H2  = (const float*)d_in[7];
    const float* sA2 = (const float*)d_in[8];
    const float* sB2 = (const float*)d_in[9];
    const float* b2  = (const float*)d_in[10];
    const float* Wl  = (const float*)d_in[11];
    const float* bl  = (const float*)d_in[12];
    float* out = (float*)d_out;
    float* ws = (float*)d_ws;
    (void)in_sizes; (void)n_in; (void)out_size; (void)ws_size;

    unsigned short* p1h = (unsigned short*)(ws + WS_P1);
    unsigned short* p1l = p1h + BATCH * NIN;
    unsigned short* p2h = (unsigned short*)(ws + WS_P2);
    unsigned short* p2l = p2h + BATCH * NFULL;

    // 1. fused cumprod + prep: c/d vectors, q1, gp1, q2, gp2, p1 (hi/lo)
    prep_fused<<<160, 256, 0, stream>>>(x, G1, H1, G2, H2, sA1, sB1, sA2, sB2, ws);

    // 2. Both rank-K GEMMs in one launch (z=0: Pt1 1024x4096, z=1: P2M 512x4096)
    gemm_rank_kernel<<<dim3(64, 16, 2), 256, 0, stream>>>(ws);

    // 3. Chunk-local diagonal scans (64-row chunks) + chunk totals
    diag_scan_p1<<<dim3(20, NCH1, 2), 256, 0, stream>>>(ws);
    //    chunk totals -> exclusive offsets (in place)
    off_prefix<<<dim3(20, 1, 2), 256, 0, stream>>>(ws);

    // 4. GEMM2 layer 1 (split-precision bf16 MFMA) -> 4 partial slices
    gemm2_l1_mfma<<<dim3(64, 1, 4), 512, 0, stream>>>(ws + WS_PT1, ws + WS_CT1,
                                                      p1h, p1l, ws + WS_VP1);
    //    reduce + epilogue -> p2 (hi/lo planes)
    reduce_l1_kernel<<<512, 256, 0, stream>>>(ws + WS_VP1, ws + WS_C1, b1, ws + WS_D2,
                                              p2h, p2l);

    // 5. GEMM2 layer 2 (split-precision bf16 MFMA, split-K=32) -> partials
    gemm2_l2_mfma<<<dim3(8, 1, 32), 512, 0, stream>>>(p2h, p2l, ws + WS_P2M,
                                                      ws + WS_CT2, ws + WS_VP2);

    // 6. fused reduce + epilogue + logits
    fused_out_kernel<<<BATCH, 256, 0, stream>>>(ws + WS_VP2, ws + WS_C2, b2, Wl, bl, out);
}